// Round 4
// baseline (881.671 us; speedup 1.0000x reference)
//
#include <hip/hip_runtime.h>
#include <hip/hip_bf16.h>

#define N_NODES 100000
#define N_EDGES 3200000
#define N_GRAPHS 256
#define D_IN 320
#define D_H 64
#define SCAN_B 256
#define BIN_SHIFT 5                       // 32 dst nodes per bin
#define N_BINS (N_NODES >> BIN_SHIFT)     // 3125 (exact)
#define BIN_CAP 2048                      // >30 sigma above mean 1024

// ---------------- CSR build ----------------

__global__ void k_count(const int* __restrict__ dst, int* __restrict__ cnt) {
    int e = blockIdx.x * blockDim.x + threadIdx.x;
    if (e < N_EDGES) atomicAdd(&cnt[dst[e]], 1);
}

__global__ void k_dinv(const int* __restrict__ cnt, float* __restrict__ dinv) {
    int i = blockIdx.x * blockDim.x + threadIdx.x;
    if (i < N_NODES) {
        float deg = (float)(cnt[i] + 1);   // +1 self loop
        dinv[i] = 1.0f / sqrtf(deg);
    }
}

__global__ void k_scan1(const int* __restrict__ cnt, int* __restrict__ rowptr,
                        int* __restrict__ bsum) {
    __shared__ int tmp[SCAN_B];
    int idx = blockIdx.x * SCAN_B + threadIdx.x;
    int v = (idx < N_NODES) ? cnt[idx] : 0;
    tmp[threadIdx.x] = v;
    __syncthreads();
    for (int off = 1; off < SCAN_B; off <<= 1) {
        int t = (threadIdx.x >= off) ? tmp[threadIdx.x - off] : 0;
        __syncthreads();
        tmp[threadIdx.x] += t;
        __syncthreads();
    }
    if (idx < N_NODES) rowptr[idx] = tmp[threadIdx.x] - v;   // exclusive
    if (threadIdx.x == SCAN_B - 1) bsum[blockIdx.x] = tmp[threadIdx.x];
}

__global__ void k_scan2(int* __restrict__ bsum, int* __restrict__ rowptr, int nb) {
    __shared__ int tmp[512];
    int v = (threadIdx.x < nb) ? bsum[threadIdx.x] : 0;
    tmp[threadIdx.x] = v;
    __syncthreads();
    for (int off = 1; off < 512; off <<= 1) {
        int t = (threadIdx.x >= off) ? tmp[threadIdx.x - off] : 0;
        __syncthreads();
        tmp[threadIdx.x] += t;
        __syncthreads();
    }
    if (threadIdx.x < nb) bsum[threadIdx.x] = tmp[threadIdx.x] - v;  // exclusive
    if (threadIdx.x == 511) rowptr[N_NODES] = tmp[511];              // total = E
}

__global__ void k_scan3(int* __restrict__ rowptr, const int* __restrict__ bsum) {
    int idx = blockIdx.x * SCAN_B + threadIdx.x;
    if (idx < N_NODES) rowptr[idx] += bsum[blockIdx.x];
}

// scatter edges into dst-aligned bins; pack (dst&31)<<17 | src into 4B
__global__ void k_scat(const int* __restrict__ src, const int* __restrict__ dst,
                       const int* __restrict__ rowptr, int* __restrict__ bcur,
                       int* __restrict__ ebuf) {
    int e = blockIdx.x * blockDim.x + threadIdx.x;
    if (e >= N_EDGES) return;
    int d = dst[e], s = src[e];
    int b = d >> BIN_SHIFT;
    int pos = atomicAdd(&bcur[b], 1);
    int base = rowptr[b << BIN_SHIFT];       // bin base == rowptr of first dst in bin
    ebuf[base + pos] = ((d & 31) << 17) | s;
}

// one block per bin: counting-sort the bin's edges by dst into LDS, write coalesced
__global__ __launch_bounds__(256) void k_sortbin(const int* __restrict__ rowptr,
                                                 const int* __restrict__ ebuf,
                                                 int* __restrict__ col) {
    __shared__ int lc[32];
    __shared__ int lds_col[BIN_CAP];
    int b = blockIdx.x;
    int d0 = b << BIN_SHIFT;
    int e0 = rowptr[d0];
    int e1 = rowptr[d0 + 32];                // all bins full: 3125*32 == N_NODES
    if (threadIdx.x < 32) lc[threadIdx.x] = rowptr[d0 + threadIdx.x] - e0;
    __syncthreads();
    for (int i = e0 + threadIdx.x; i < e1; i += 256) {
        int pk = ebuf[i];
        int dl = pk >> 17;
        int s  = pk & 0x1FFFF;
        int p = atomicAdd(&lc[dl], 1);
        if (p < BIN_CAP) lds_col[p] = s;
    }
    __syncthreads();
    int n = e1 - e0;
    for (int i = threadIdx.x; i < n; i += 256) col[e0 + i] = lds_col[i];
}

// ---------------- tiled GEMM transform ----------------
// u[node][f] = (A[node,:] @ W)[f] * dinv[node]
template<int K>
__global__ __launch_bounds__(256) void k_gemm(const float* __restrict__ A,
                                              const float* __restrict__ W,
                                              const float* __restrict__ dinv,
                                              float* __restrict__ u) {
    __shared__ __align__(16) float xt[64][68];   // transposed x chunk [k][node]
    __shared__ __align__(16) float ws[64][68];   // W chunk [k][feature]
    int t = threadIdx.x;
    int ti = t & 15;        // feature group: features 4*ti .. 4*ti+3
    int tj = t >> 4;        // node group:    nodes    4*tj .. 4*tj+3
    int node0 = blockIdx.x * 64;
    float acc[4][4] = {{0.f}};

    for (int kc = 0; kc < K; kc += 64) {
        if (kc) __syncthreads();
#pragma unroll
        for (int p = 0; p < 4; ++p) {
            int m = tj + 16 * p;                       // 0..63
            int node = node0 + m;
            if (node >= N_NODES) node = N_NODES - 1;   // clamp (stores guarded)
            float4 v = *(const float4*)(A + (size_t)node * K + kc + 4 * ti);
            xt[4 * ti + 0][m] = v.x;
            xt[4 * ti + 1][m] = v.y;
            xt[4 * ti + 2][m] = v.z;
            xt[4 * ti + 3][m] = v.w;
            float4 wv = *(const float4*)(W + (size_t)(kc + m) * D_H + 4 * ti);
            *(float4*)&ws[m][4 * ti] = wv;
        }
        __syncthreads();
#pragma unroll 16
        for (int k = 0; k < 64; ++k) {
            float4 xv = *(const float4*)&xt[k][4 * tj];
            float4 wv = *(const float4*)&ws[k][4 * ti];
            float xa[4] = {xv.x, xv.y, xv.z, xv.w};
            float wa[4] = {wv.x, wv.y, wv.z, wv.w};
#pragma unroll
            for (int i = 0; i < 4; ++i)
#pragma unroll
                for (int j = 0; j < 4; ++j)
                    acc[i][j] = fmaf(xa[i], wa[j], acc[i][j]);
        }
    }
#pragma unroll
    for (int i = 0; i < 4; ++i) {
        int node = node0 + 4 * tj + i;
        if (node < N_NODES) {
            float dv = dinv[node];
            float4 o = make_float4(acc[i][0] * dv, acc[i][1] * dv,
                                   acc[i][2] * dv, acc[i][3] * dv);
            *(float4*)(u + (size_t)node * D_H + 4 * ti) = o;
        }
    }
}

// ---------------- aggregation ----------------

__device__ __forceinline__ float agg_gather(const float* __restrict__ u,
                                            const int* __restrict__ col,
                                            int beg, int end, int lane, float acc) {
    int e = beg;
    for (; e + 7 < end; e += 8) {                // 8 independent gathers in flight
        int s0 = col[e],     s1 = col[e + 1], s2 = col[e + 2], s3 = col[e + 3];
        int s4 = col[e + 4], s5 = col[e + 5], s6 = col[e + 6], s7 = col[e + 7];
        float v0 = u[(size_t)s0 * D_H + lane];
        float v1 = u[(size_t)s1 * D_H + lane];
        float v2 = u[(size_t)s2 * D_H + lane];
        float v3 = u[(size_t)s3 * D_H + lane];
        float v4 = u[(size_t)s4 * D_H + lane];
        float v5 = u[(size_t)s5 * D_H + lane];
        float v6 = u[(size_t)s6 * D_H + lane];
        float v7 = u[(size_t)s7 * D_H + lane];
        acc += ((v0 + v1) + (v2 + v3)) + ((v4 + v5) + (v6 + v7));
    }
    for (; e < end; ++e) acc += u[(size_t)col[e] * D_H + lane];
    return acc;
}

// h[i] = relu( dinv[i] * (sum_{src in N(i)} u[src] + u[i]) + b )
__global__ __launch_bounds__(256) void k_agg(const float* __restrict__ u,
                                             const int* __restrict__ rowptr,
                                             const int* __restrict__ col,
                                             const float* __restrict__ dinv,
                                             const float* __restrict__ b,
                                             float* __restrict__ h) {
    int lane = threadIdx.x & 63;
    int node = (blockIdx.x * blockDim.x + threadIdx.x) >> 6;
    if (node >= N_NODES) return;
    float acc = u[(size_t)node * D_H + lane];    // self loop
    acc = agg_gather(u, col, rowptr[node], rowptr[node + 1], lane, acc);
    acc = acc * dinv[node] + b[lane];
    h[(size_t)node * D_H + lane] = fmaxf(acc, 0.0f);
}

// layer 3 fused with the linear head: val[i] = dot(agg_row + b3, Wl)
__global__ __launch_bounds__(256) void k_agg_dot(const float* __restrict__ u,
                                                 const int* __restrict__ rowptr,
                                                 const int* __restrict__ col,
                                                 const float* __restrict__ dinv,
                                                 const float* __restrict__ b,
                                                 const float* __restrict__ Wl,
                                                 float* __restrict__ val) {
    int lane = threadIdx.x & 63;
    int node = (blockIdx.x * blockDim.x + threadIdx.x) >> 6;
    if (node >= N_NODES) return;
    float acc = u[(size_t)node * D_H + lane];    // self loop
    acc = agg_gather(u, col, rowptr[node], rowptr[node + 1], lane, acc);
    acc = acc * dinv[node] + b[lane];
    float v = acc * Wl[lane];
#pragma unroll
    for (int m = 32; m > 0; m >>= 1) v += __shfl_xor(v, m, 64);
    if (lane == 0) val[node] = v;
}

// one block per graph: batch is sorted, binary-search the segment, reduce.
__global__ __launch_bounds__(256) void k_gpool(const float* __restrict__ val,
                                               const int* __restrict__ batch,
                                               const float* __restrict__ bl,
                                               float* __restrict__ out) {
    int g = blockIdx.x;
    int l = 0, r = N_NODES;                      // lower_bound(batch, g)
    while (l < r) { int m = (l + r) >> 1; if (batch[m] < g) l = m + 1; else r = m; }
    int lo = l;
    r = N_NODES;                                 // lower_bound(batch, g+1)
    while (l < r) { int m = (l + r) >> 1; if (batch[m] < g + 1) l = m + 1; else r = m; }
    int hi = l;
    float s = 0.0f;
    for (int i = lo + threadIdx.x; i < hi; i += 256) s += val[i];
#pragma unroll
    for (int m = 32; m > 0; m >>= 1) s += __shfl_xor(s, m, 64);
    __shared__ float red[4];
    int wid = threadIdx.x >> 6, lane = threadIdx.x & 63;
    if (lane == 0) red[wid] = s;
    __syncthreads();
    if (threadIdx.x == 0) {
        float t = red[0] + red[1] + red[2] + red[3];
        out[g] = t / fmaxf((float)(hi - lo), 1.0f) + bl[0];
    }
}

// ---------------- launch ----------------

extern "C" void kernel_launch(void* const* d_in, const int* in_sizes, int n_in,
                              void* d_out, int out_size, void* d_ws, size_t ws_size,
                              hipStream_t stream) {
    const float* x   = (const float*)d_in[0];
    const int*   ei  = (const int*)d_in[1];
    const int*   bat = (const int*)d_in[2];
    const float* W1  = (const float*)d_in[3];
    const float* b1  = (const float*)d_in[4];
    const float* W2  = (const float*)d_in[5];
    const float* b2  = (const float*)d_in[6];
    const float* W3  = (const float*)d_in[7];
    const float* b3  = (const float*)d_in[8];
    const float* Wl  = (const float*)d_in[9];
    const float* bl  = (const float*)d_in[10];
    float* out = (float*)d_out;

    char* p = (char*)d_ws;
    auto alloc = [&](size_t bytes) -> void* {
        void* r = (void*)p;
        p += (bytes + 255) & ~(size_t)255;
        return r;
    };
    int*   cnt    = (int*)alloc((size_t)N_NODES * 4);
    int*   rowptr = (int*)alloc((size_t)(N_NODES + 1) * 4);
    float* dinv   = (float*)alloc((size_t)N_NODES * 4);
    int*   colb   = (int*)alloc((size_t)N_EDGES * 4);
    int*   ebuf   = (int*)alloc((size_t)N_EDGES * 4);
    int*   bcur   = (int*)alloc((size_t)N_BINS * 4);
    int*   bsum   = (int*)alloc((size_t)512 * 4);
    float* u      = (float*)alloc((size_t)N_NODES * D_H * 4);
    float* h      = (float*)alloc((size_t)N_NODES * D_H * 4);
    float* val    = (float*)alloc((size_t)N_NODES * 4);

    hipMemsetAsync(cnt, 0, (size_t)N_NODES * 4, stream);
    hipMemsetAsync(bcur, 0, (size_t)N_BINS * 4, stream);

    const int* srcp = ei;
    const int* dstp = ei + N_EDGES;

    int ebl = (N_EDGES + 255) / 256;
    int nbl = (N_NODES + 255) / 256;
    int nb  = (N_NODES + SCAN_B - 1) / SCAN_B;      // 391
    int wbl = (N_NODES * 64 + 255) / 256;           // one wave per node
    int gbl = (N_NODES + 63) / 64;                  // GEMM blocks

    k_count<<<ebl, 256, 0, stream>>>(dstp, cnt);
    k_dinv<<<nbl, 256, 0, stream>>>(cnt, dinv);
    k_scan1<<<nb, SCAN_B, 0, stream>>>(cnt, rowptr, bsum);
    k_scan2<<<1, 512, 0, stream>>>(bsum, rowptr, nb);
    k_scan3<<<nb, SCAN_B, 0, stream>>>(rowptr, bsum);
    k_scat<<<ebl, 256, 0, stream>>>(srcp, dstp, rowptr, bcur, ebuf);
    k_sortbin<<<N_BINS, 256, 0, stream>>>(rowptr, ebuf, colb);

    // layer 1: 320 -> 64
    k_gemm<D_IN><<<gbl, 256, 0, stream>>>(x, W1, dinv, u);
    k_agg<<<wbl, 256, 0, stream>>>(u, rowptr, colb, dinv, b1, h);
    // layer 2: 64 -> 64
    k_gemm<D_H><<<gbl, 256, 0, stream>>>(h, W2, dinv, u);
    k_agg<<<wbl, 256, 0, stream>>>(u, rowptr, colb, dinv, b2, h);
    // layer 3: 64 -> 64, fused with linear head dot
    k_gemm<D_H><<<gbl, 256, 0, stream>>>(h, W3, dinv, u);
    k_agg_dot<<<wbl, 256, 0, stream>>>(u, rowptr, colb, dinv, b3, Wl, val);

    // pooling: one block per graph, no atomics
    k_gpool<<<N_GRAPHS, 256, 0, stream>>>(val, bat, bl, out);
}

// Round 5
// 541.351 us; speedup vs baseline: 1.6286x; 1.6286x over previous
//
#include <hip/hip_runtime.h>
#include <hip/hip_bf16.h>

#define N_NODES 100000
#define N_EDGES 3200000
#define N_GRAPHS 256
#define D_IN 320
#define D_H 64

#define NBIN 391                    // ceil(N_NODES / 256) bins of 256 dst nodes
#define BIN_CAP 12288               // mean bin load 8186, sigma~90 -> +45 sigma
#define HIST_BLOCKS 256
#define HIST_CHUNK ((N_EDGES + HIST_BLOCKS - 1) / HIST_BLOCKS)
#define PART_BLOCKS 200
#define PART_CHUNK ((N_EDGES + PART_BLOCKS - 1) / PART_BLOCKS)   // 16000

// ---------------- CSR build (block-private chunk partition) ----------------

// global 391-bin histogram with LDS pre-aggregation
__global__ __launch_bounds__(256) void k_hist(const int* __restrict__ dst,
                                              int* __restrict__ ghist) {
    __shared__ int lh[NBIN];
    for (int i = threadIdx.x; i < NBIN; i += 256) lh[i] = 0;
    __syncthreads();
    int beg = blockIdx.x * HIST_CHUNK;
    int end = min(beg + HIST_CHUNK, N_EDGES);
    for (int e = beg + threadIdx.x; e < end; e += 256)
        atomicAdd(&lh[dst[e] >> 8], 1);
    __syncthreads();
    for (int i = threadIdx.x; i < NBIN; i += 256)
        if (lh[i]) atomicAdd(&ghist[i], lh[i]);
}

// single-block exclusive scan of the 391 bin totals
__global__ __launch_bounds__(512) void k_scanbins(const int* __restrict__ ghist,
                                                  int* __restrict__ binbase,
                                                  int* __restrict__ gcur,
                                                  int* __restrict__ rowptr) {
    __shared__ int sa[512], sb[512];
    int t = threadIdx.x;
    int v = (t < NBIN) ? ghist[t] : 0;
    sa[t] = v;
    __syncthreads();
    int* in = sa; int* out = sb;
    for (int off = 1; off < 512; off <<= 1) {
        out[t] = in[t] + (t >= off ? in[t - off] : 0);
        __syncthreads();
        int* tmp = in; in = out; out = tmp;
    }
    int excl = in[t] - v;
    if (t < NBIN) { binbase[t] = excl; gcur[t] = excl; }
    if (t == 511) { binbase[NBIN] = in[511]; rowptr[N_NODES] = in[511]; }
}

// partition edges into 391 bins; each block reserves a private contiguous
// chunk per bin (one global atomic per (block,bin)) -> every ebuf cacheline
// is written by exactly one block, once.
__global__ __launch_bounds__(256) void k_part(const int* __restrict__ src,
                                              const int* __restrict__ dst,
                                              int* __restrict__ gcur,
                                              int* __restrict__ ebuf) {
    __shared__ int lh[NBIN], gb[NBIN], cur[NBIN];
    for (int i = threadIdx.x; i < NBIN; i += 256) { lh[i] = 0; cur[i] = 0; }
    __syncthreads();
    int beg = blockIdx.x * PART_CHUNK;
    int end = min(beg + PART_CHUNK, N_EDGES);
    for (int e = beg + threadIdx.x; e < end; e += 256)
        atomicAdd(&lh[dst[e] >> 8], 1);
    __syncthreads();
    for (int i = threadIdx.x; i < NBIN; i += 256)
        gb[i] = lh[i] ? atomicAdd(&gcur[i], lh[i]) : 0;
    __syncthreads();
    for (int e = beg + threadIdx.x; e < end; e += 256) {
        int d = dst[e], s = src[e];
        int bin = d >> 8;
        int r = atomicAdd(&cur[bin], 1);
        ebuf[gb[bin] + r] = ((d & 255) << 17) | s;   // dst-low-8 | src(17b)
    }
}

// one block per bin: LDS counting-sort by dst; writes col coalesced and
// emits rowptr + dinv for its 256 nodes (replaces k_count/k_dinv/scans).
__global__ __launch_bounds__(256) void k_sortbin(const int* __restrict__ binbase,
                                                 const int* __restrict__ ebuf,
                                                 int* __restrict__ col,
                                                 int* __restrict__ rowptr,
                                                 float* __restrict__ dinv) {
    __shared__ int hc[256], sc[256], sa[256], sb[256];
    __shared__ int scol[BIN_CAP];
    int b = blockIdx.x, t = threadIdx.x;
    int d0 = b << 8;
    int e0 = binbase[b], e1 = binbase[b + 1];
    hc[t] = 0;
    __syncthreads();
    for (int i = e0 + t; i < e1; i += 256)
        atomicAdd(&hc[ebuf[i] >> 17], 1);
    __syncthreads();
    sa[t] = hc[t];
    __syncthreads();
    int* in = sa; int* out = sb;
    for (int o = 1; o < 256; o <<= 1) {
        out[t] = in[t] + (t >= o ? in[t - o] : 0);
        __syncthreads();
        int* tm = in; in = out; out = tm;
    }
    int excl = in[t] - hc[t];
    sc[t] = excl;
    int node = d0 + t;
    if (node < N_NODES) {
        rowptr[node] = e0 + excl;
        dinv[node] = rsqrtf((float)(hc[t] + 1));   // +1 self loop
    }
    __syncthreads();
    for (int i = e0 + t; i < e1; i += 256) {
        int pk = ebuf[i];
        int p = atomicAdd(&sc[pk >> 17], 1);
        if (p < BIN_CAP) scol[p] = pk & 0x1FFFF;
    }
    __syncthreads();
    int n = e1 - e0;
    for (int i = t; i < n; i += 256) col[e0 + i] = scol[i];
}

// ---------------- tiled GEMM transform ----------------
// u[node][f] = (A[node,:] @ W)[f] * dinv[node]
template<int K>
__global__ __launch_bounds__(256) void k_gemm(const float* __restrict__ A,
                                              const float* __restrict__ W,
                                              const float* __restrict__ dinv,
                                              float* __restrict__ u) {
    __shared__ __align__(16) float xt[64][68];   // transposed x chunk [k][node]
    __shared__ __align__(16) float ws[64][68];   // W chunk [k][feature]
    int t = threadIdx.x;
    int ti = t & 15;        // feature group: features 4*ti .. 4*ti+3
    int tj = t >> 4;        // node group:    nodes    4*tj .. 4*tj+3
    int node0 = blockIdx.x * 64;
    float acc[4][4] = {{0.f}};

    for (int kc = 0; kc < K; kc += 64) {
        if (kc) __syncthreads();
#pragma unroll
        for (int p = 0; p < 4; ++p) {
            int m = tj + 16 * p;                       // 0..63
            int node = node0 + m;
            if (node >= N_NODES) node = N_NODES - 1;   // clamp (stores guarded)
            float4 v = *(const float4*)(A + (size_t)node * K + kc + 4 * ti);
            xt[4 * ti + 0][m] = v.x;
            xt[4 * ti + 1][m] = v.y;
            xt[4 * ti + 2][m] = v.z;
            xt[4 * ti + 3][m] = v.w;
            float4 wv = *(const float4*)(W + (size_t)(kc + m) * D_H + 4 * ti);
            *(float4*)&ws[m][4 * ti] = wv;
        }
        __syncthreads();
#pragma unroll 16
        for (int k = 0; k < 64; ++k) {
            float4 xv = *(const float4*)&xt[k][4 * tj];
            float4 wv = *(const float4*)&ws[k][4 * ti];
            float xa[4] = {xv.x, xv.y, xv.z, xv.w};
            float wa[4] = {wv.x, wv.y, wv.z, wv.w};
#pragma unroll
            for (int i = 0; i < 4; ++i)
#pragma unroll
                for (int j = 0; j < 4; ++j)
                    acc[i][j] = fmaf(xa[i], wa[j], acc[i][j]);
        }
    }
#pragma unroll
    for (int i = 0; i < 4; ++i) {
        int node = node0 + 4 * tj + i;
        if (node < N_NODES) {
            float dv = dinv[node];
            float4 o = make_float4(acc[i][0] * dv, acc[i][1] * dv,
                                   acc[i][2] * dv, acc[i][3] * dv);
            *(float4*)(u + (size_t)node * D_H + 4 * ti) = o;
        }
    }
}

// ---------------- aggregation ----------------

__device__ __forceinline__ float agg_gather(const float* __restrict__ u,
                                            const int* __restrict__ col,
                                            int beg, int end, int lane, float acc) {
    int e = beg;
    for (; e + 7 < end; e += 8) {                // 8 independent gathers in flight
        int s0 = col[e],     s1 = col[e + 1], s2 = col[e + 2], s3 = col[e + 3];
        int s4 = col[e + 4], s5 = col[e + 5], s6 = col[e + 6], s7 = col[e + 7];
        float v0 = u[(size_t)s0 * D_H + lane];
        float v1 = u[(size_t)s1 * D_H + lane];
        float v2 = u[(size_t)s2 * D_H + lane];
        float v3 = u[(size_t)s3 * D_H + lane];
        float v4 = u[(size_t)s4 * D_H + lane];
        float v5 = u[(size_t)s5 * D_H + lane];
        float v6 = u[(size_t)s6 * D_H + lane];
        float v7 = u[(size_t)s7 * D_H + lane];
        acc += ((v0 + v1) + (v2 + v3)) + ((v4 + v5) + (v6 + v7));
    }
    for (; e < end; ++e) acc += u[(size_t)col[e] * D_H + lane];
    return acc;
}

// h[i] = relu( dinv[i] * (sum_{src in N(i)} u[src] + u[i]) + b )
__global__ __launch_bounds__(256) void k_agg(const float* __restrict__ u,
                                             const int* __restrict__ rowptr,
                                             const int* __restrict__ col,
                                             const float* __restrict__ dinv,
                                             const float* __restrict__ b,
                                             float* __restrict__ h) {
    int lane = threadIdx.x & 63;
    int node = (blockIdx.x * blockDim.x + threadIdx.x) >> 6;
    if (node >= N_NODES) return;
    float acc = u[(size_t)node * D_H + lane];    // self loop
    acc = agg_gather(u, col, rowptr[node], rowptr[node + 1], lane, acc);
    acc = acc * dinv[node] + b[lane];
    h[(size_t)node * D_H + lane] = fmaxf(acc, 0.0f);
}

// layer 3 fused with the linear head: val[i] = dot(agg_row + b3, Wl)
__global__ __launch_bounds__(256) void k_agg_dot(const float* __restrict__ u,
                                                 const int* __restrict__ rowptr,
                                                 const int* __restrict__ col,
                                                 const float* __restrict__ dinv,
                                                 const float* __restrict__ b,
                                                 const float* __restrict__ Wl,
                                                 float* __restrict__ val) {
    int lane = threadIdx.x & 63;
    int node = (blockIdx.x * blockDim.x + threadIdx.x) >> 6;
    if (node >= N_NODES) return;
    float acc = u[(size_t)node * D_H + lane];    // self loop
    acc = agg_gather(u, col, rowptr[node], rowptr[node + 1], lane, acc);
    acc = acc * dinv[node] + b[lane];
    float v = acc * Wl[lane];
#pragma unroll
    for (int m = 32; m > 0; m >>= 1) v += __shfl_xor(v, m, 64);
    if (lane == 0) val[node] = v;
}

// one block per graph: batch is sorted, binary-search the segment, reduce.
__global__ __launch_bounds__(256) void k_gpool(const float* __restrict__ val,
                                               const int* __restrict__ batch,
                                               const float* __restrict__ bl,
                                               float* __restrict__ out) {
    int g = blockIdx.x;
    int l = 0, r = N_NODES;                      // lower_bound(batch, g)
    while (l < r) { int m = (l + r) >> 1; if (batch[m] < g) l = m + 1; else r = m; }
    int lo = l;
    r = N_NODES;                                 // lower_bound(batch, g+1)
    while (l < r) { int m = (l + r) >> 1; if (batch[m] < g + 1) l = m + 1; else r = m; }
    int hi = l;
    float s = 0.0f;
    for (int i = lo + threadIdx.x; i < hi; i += 256) s += val[i];
#pragma unroll
    for (int m = 32; m > 0; m >>= 1) s += __shfl_xor(s, m, 64);
    __shared__ float red[4];
    int wid = threadIdx.x >> 6, lane = threadIdx.x & 63;
    if (lane == 0) red[wid] = s;
    __syncthreads();
    if (threadIdx.x == 0) {
        float t = red[0] + red[1] + red[2] + red[3];
        out[g] = t / fmaxf((float)(hi - lo), 1.0f) + bl[0];
    }
}

// ---------------- launch ----------------

extern "C" void kernel_launch(void* const* d_in, const int* in_sizes, int n_in,
                              void* d_out, int out_size, void* d_ws, size_t ws_size,
                              hipStream_t stream) {
    const float* x   = (const float*)d_in[0];
    const int*   ei  = (const int*)d_in[1];
    const int*   bat = (const int*)d_in[2];
    const float* W1  = (const float*)d_in[3];
    const float* b1  = (const float*)d_in[4];
    const float* W2  = (const float*)d_in[5];
    const float* b2  = (const float*)d_in[6];
    const float* W3  = (const float*)d_in[7];
    const float* b3  = (const float*)d_in[8];
    const float* Wl  = (const float*)d_in[9];
    const float* bl  = (const float*)d_in[10];
    float* out = (float*)d_out;

    char* p = (char*)d_ws;
    auto alloc = [&](size_t bytes) -> void* {
        void* r = (void*)p;
        p += (bytes + 255) & ~(size_t)255;
        return r;
    };
    int*   ghist   = (int*)alloc((size_t)NBIN * 4);
    int*   binbase = (int*)alloc((size_t)(NBIN + 1) * 4);
    int*   gcur    = (int*)alloc((size_t)NBIN * 4);
    int*   rowptr  = (int*)alloc((size_t)(N_NODES + 1) * 4);
    float* dinv    = (float*)alloc((size_t)N_NODES * 4);
    int*   colb    = (int*)alloc((size_t)N_EDGES * 4);
    int*   ebuf    = (int*)alloc((size_t)N_EDGES * 4);
    float* u       = (float*)alloc((size_t)N_NODES * D_H * 4);
    float* h       = (float*)alloc((size_t)N_NODES * D_H * 4);
    float* val     = (float*)alloc((size_t)N_NODES * 4);

    hipMemsetAsync(ghist, 0, (size_t)NBIN * 4, stream);

    const int* srcp = ei;
    const int* dstp = ei + N_EDGES;

    int wbl = (N_NODES * 64 + 255) / 256;           // one wave per node
    int gbl = (N_NODES + 63) / 64;                  // GEMM blocks

    // CSR build
    k_hist<<<HIST_BLOCKS, 256, 0, stream>>>(dstp, ghist);
    k_scanbins<<<1, 512, 0, stream>>>(ghist, binbase, gcur, rowptr);
    k_part<<<PART_BLOCKS, 256, 0, stream>>>(srcp, dstp, gcur, ebuf);
    k_sortbin<<<NBIN, 256, 0, stream>>>(binbase, ebuf, colb, rowptr, dinv);

    // layer 1: 320 -> 64
    k_gemm<D_IN><<<gbl, 256, 0, stream>>>(x, W1, dinv, u);
    k_agg<<<wbl, 256, 0, stream>>>(u, rowptr, colb, dinv, b1, h);
    // layer 2: 64 -> 64
    k_gemm<D_H><<<gbl, 256, 0, stream>>>(h, W2, dinv, u);
    k_agg<<<wbl, 256, 0, stream>>>(u, rowptr, colb, dinv, b2, h);
    // layer 3: 64 -> 64, fused with linear head dot
    k_gemm<D_H><<<gbl, 256, 0, stream>>>(h, W3, dinv, u);
    k_agg_dot<<<wbl, 256, 0, stream>>>(u, rowptr, colb, dinv, b3, Wl, val);

    // pooling: one block per graph, no atomics
    k_gpool<<<N_GRAPHS, 256, 0, stream>>>(val, bat, bl, out);
}